// Round 2
// baseline (398.859 us; speedup 1.0000x reference)
//
#include <hip/hip_runtime.h>
#include <math.h>

#define B_SZ 1024
#define K_SZ 24
#define H_SZ 64
#define NVIS 256

typedef float vfloat4 __attribute__((ext_vector_type(4)));

// ---------------------------------------------------------------------------
// R5 discovery (from rocprof top-5): the timed region includes a ~266 us
// harness poison-fill (1.57 GB @ 6.2 TB/s) every iteration. gs_main is absent
// from top-5 => gs_main < 259 us; arithmetic gives gs_main ~ 120 us.
// So the kernel-side gap is 2x (120 vs 64.5 us store floor), not 6x.
//
// R5 theory: the 2x is phase serialization. Old gs_main gated its store phase
// behind TWO block-wide barriers + a block-shared LDS tile (zero -> atomics ->
// readback), so the store pipe starves whenever the 8 resident blocks/CU
// cluster in non-store phases.
//
// R5 fix: wave-private bands, ZERO barriers. Each of the 4 waves owns a
// 16-row band (private 4 KB LDS quarter). Spike loop: readlane -> UNIFORM
// skip tests (scalar branch); a matched spike's 25 taps map to lanes 0..24
// (one ds_add_f32 + one coalesced 100 B weight load per spike). ~150 instrs
// per wave total, fully hidden under other waves' stores. Waves never sync.
// ---------------------------------------------------------------------------

__global__ __launch_bounds__(256) void gs_prep(
    const float2* __restrict__ x,         // [B*K] (x,y)
    const int*    __restrict__ vis_b,     // [256]
    const int*    __restrict__ vis_k,     // [256]
    int*          __restrict__ spike_tab) // [B*K] packed y*64+x or -1
{
    __shared__ unsigned char killf[256];
    const int tid  = threadIdx.x;
    const int base = blockIdx.x * 256;
    const int bk   = base + tid;               // exactly B*K threads
    killf[tid] = 0;

    // spike position: match jnp.round((v+1.0)*0.5*(H-1)); rintf = half-to-even
    const float2 c = x[bk];
    const int cx = (int)rintf((c.x + 1.0f) * 0.5f * 63.0f);
    const int cy = (int)rintf((c.y + 1.0f) * 0.5f * 63.0f);
    // in-range AND torch quirk (x-coord != 0) => cx in [1,64)
    const bool ok = (cx >= 1) & (cx < H_SZ) & (cy >= 0) & (cy < H_SZ);
    int s = ok ? (cy * H_SZ + cx) : -1;

    // kill scatter: code == bk <=> this block's flag slot (racy same-value ok)
    const int code = vis_b[tid] * K_SZ + vis_k[tid];
    __syncthreads();                            // killf init complete
    const unsigned local = (unsigned)(code - base);
    if (local < 256u) killf[local] = 1;
    __syncthreads();
    if (killf[tid]) s = -1;
    spike_tab[bk] = s;
}

__global__ __launch_bounds__(256) void gs_main(
    const int*   __restrict__ spike_tab, // [B*K]
    const float* __restrict__ w,         // [K,K,5,5] OIHW, 600 floats per o
    float*       __restrict__ out)       // [B,K,64,64]
{
    // 4 waves x private 4 KB band tile = 16 KB; 8 blocks/CU (wave-capped)
    __shared__ float tile[4][16 * H_SZ];
    const int bid  = blockIdx.x;
    const int b    = bid / K_SZ;
    const int o    = bid - b * K_SZ;
    const int tid  = threadIdx.x;
    const int wv   = tid >> 6;            // wave 0..3
    const int l    = tid & 63;            // lane
    const int band = wv << 4;             // first row of this wave's band

    float* t = tile[wv];

    // lane-personal spike code (lanes 0..23); issue early, latency overlaps zero
    const int* sp = spike_tab + b * K_SZ;
    const int myspike = (l < K_SZ) ? sp[l] : -1;

    // zero the wave-private 4 KB tile: 64 lanes x 4 x float4
    vfloat4* t4 = (vfloat4*)t;
    const vfloat4 z = {0.f, 0.f, 0.f, 0.f};
#pragma unroll
    for (int r = 0; r < 4; ++r) t4[r * 64 + l] = z;

    // tap geometry: lane l<25 owns patch cell (di,dj)
    const int  di    = l / 5;
    const int  dj    = l - di * 5;
    const bool istap = (l < 25);

    const float* wo = w + o * (K_SZ * 25);

#pragma unroll
    for (int s = 0; s < K_SZ; ++s) {
        const int code = __builtin_amdgcn_readlane(myspike, s); // uniform
        if (code < 0) continue;                                 // scalar skip
        const int y = code >> 6;
        // patch rows [y-2, y+2] vs band [band, band+16): uniform skip
        if ((y + 2 < band) | (y - 2 >= band + 16)) continue;
        const int x = code & 63;
        const int i = y + 2 - di;          // target row of this lane's tap
        const int j = x + 2 - dj;          // target col
        const unsigned ri = (unsigned)(i - band);
        if (istap & (ri < 16u) & ((unsigned)j < (unsigned)H_SZ)) {
            const float wt = wo[s * 25 + l];    // coalesced 100 B, L2-hot
            atomicAdd(&t[ri * H_SZ + j], wt);   // ds_add_f32, intra-wave only
        }
    }

    // stream the wave's band out: 4 x (64 lanes x 16 B) = 4 KB, coalesced
    vfloat4* o4 = (vfloat4*)(out + ((size_t)bid << 12) + (size_t)(band * H_SZ));
#pragma unroll
    for (int r = 0; r < 4; ++r) {
        const int idx = r * 64 + l;
        o4[idx] = t4[idx];
    }
}

extern "C" void kernel_launch(void* const* d_in, const int* in_sizes, int n_in,
                              void* d_out, int out_size, void* d_ws, size_t ws_size,
                              hipStream_t stream) {
    const float2* x     = (const float2*)d_in[0];
    const float*  w     = (const float*)d_in[1];
    const int*    vis_b = (const int*)d_in[2];
    const int*    vis_k = (const int*)d_in[3];
    float*        out   = (float*)d_out;
    int*          spike_tab = (int*)d_ws;   // 24576 * 4 B = 96 KB scratch

    gs_prep<<<(B_SZ * K_SZ) / 256, 256, 0, stream>>>(x, vis_b, vis_k, spike_tab);
    gs_main<<<B_SZ * K_SZ, 256, 0, stream>>>(spike_tab, w, out);
}